// Round 3
// baseline (151.391 us; speedup 1.0000x reference)
//
#include <hip/hip_runtime.h>
#include <hip/hip_bf16.h>

#define HH 128
#define WW 128
#define CI 64
#define CO 64
#define SLS 584  // LDS row stride in bf16 elems (576 + 8 pad)

typedef __attribute__((ext_vector_type(8))) short short8;
typedef __attribute__((ext_vector_type(4))) float floatx4;

// Blocks [0,512): NCHW->NHWC transpose. Blocks [512,656): weight prep.
__global__ __launch_bounds__(256) void setup_kernel(
    const float* __restrict__ x, float* __restrict__ xT,
    const float* __restrict__ weight, const float* __restrict__ bias,
    const float* __restrict__ gamma, const float* __restrict__ beta,
    const float* __restrict__ mean, const float* __restrict__ var,
    const float* __restrict__ w_off, const float* __restrict__ b_off,
    unsigned short* __restrict__ A, unsigned short* __restrict__ w2,
    float* __restrict__ bias2, float* __restrict__ boff2) {
  __shared__ float tile[64][65];
  int bid = blockIdx.x;
  if (bid < 512) {
    int w0 = (bid & 1) * 64;
    int h = (bid >> 1) & (HH - 1);
    int b = bid >> 8;
    int tc = threadIdx.x & 63;
    int tr = threadIdx.x >> 6;
#pragma unroll
    for (int i = 0; i < 16; i++) {
      int c = i * 4 + tr;
      tile[c][tc] = x[((b * CI + c) * HH + h) * WW + w0 + tc];
    }
    __syncthreads();
#pragma unroll
    for (int i = 0; i < 16; i++) {
      int j = i * 4 + tr;
      xT[((b * HH + h) * WW + w0 + j) * CI + tc] = tile[tc][j];
    }
  } else {
    int idx = (bid - 512) * 256 + threadIdx.x;
    if (idx < 32) boff2[idx] = (idx < 27) ? b_off[idx] : 0.f;
    if (idx < CO * 576) {
      int o = idx / 576, kc = idx - o * 576;
      int k = kc >> 6, c = kc & 63;
      float inv = gamma[o] * rsqrtf(var[o] + 1e-5f);
      A[idx] = (unsigned short)__bfloat16_as_ushort(__float2bfloat16(weight[(o * CI + c) * 9 + k] * inv));
      if (kc == 0) bias2[o] = (bias[o] - mean[o]) * inv + beta[o];
      if (o < 27) w2[idx] = (unsigned short)__bfloat16_as_ushort(__float2bfloat16(w_off[o * 576 + c * 9 + k]));
      else if (o < 32) w2[idx] = 0;
    }
  }
}

// Fully fused DCN block: 16 pixels (one (b,h) row segment), 256 threads = 4 waves.
// P1 im2col patches -> P2 offset GEMM (per-wave, both oc tiles) ->
// P2.5 per-(p,k) sample params (intra-wave) -> P3 gather+blend -> P4 main GEMM.
__global__ __launch_bounds__(256) void dcn3_kernel(
    const float* __restrict__ xT, const unsigned short* __restrict__ w2,
    const float* __restrict__ boff2, const unsigned short* __restrict__ A,
    const float* __restrict__ bias2, float* __restrict__ out) {
  __shared__ __hip_bfloat16 SL[16 * SLS];  // X patches, then sampled S (bf16)
  __shared__ float omS[16 * 29];           // offset-conv outputs per pixel
  __shared__ float4 Pw[144];               // per-(p,k) corner weights (mask+valid folded)
  __shared__ int4 Po[144];                 // per-(p,k) corner element offsets (clamped)

  int bid = blockIdx.x;
  int w0 = (bid & 7) * 16;
  int h = (bid >> 3) & (HH - 1);
  int b = bid >> 10;
  int tid = threadIdx.x;
  int lane = tid & 63;
  int wave = tid >> 6;
  int c = lane;
  const float* xb = xT + b * (HH * WW * CI);

  // ---- P1: stage im2col patches X[p][kk*64+c] ----
#pragma unroll
  for (int i = 0; i < 4; i++) {
    int p = wave * 4 + i;
    int wpx = w0 + p;
#pragma unroll
    for (int dy = 0; dy < 3; dy++) {
      int y = h - 1 + dy;
      bool yok = (unsigned)y < (unsigned)HH;
#pragma unroll
      for (int dx = 0; dx < 3; dx++) {
        int xx = wpx - 1 + dx;
        bool ok = yok && ((unsigned)xx < (unsigned)WW);
        float v = 0.f;
        if (ok) v = xb[(y * WW + xx) * CI + c];
        SL[p * SLS + (dy * 3 + dx) * 64 + c] = __float2bfloat16(v);
      }
    }
  }
  __syncthreads();

  int r16 = lane & 15;
  int quad = lane >> 4;

  // ---- P2: offset conv GEMM. Every wave computes both oc tiles (dup MFMA is cheap);
  //          writes omS only for its own 4 pixels -> intra-wave dependency only. ----
  floatx4 t0 = *(const floatx4*)(boff2 + quad * 4);
  floatx4 t1 = *(const floatx4*)(boff2 + 16 + quad * 4);
  {
    const unsigned short* a0p = w2 + r16 * 576 + quad * 8;
    const unsigned short* a1p = w2 + (16 + r16) * 576 + quad * 8;
    const __hip_bfloat16* bp = &SL[r16 * SLS + quad * 8];
#pragma unroll
    for (int kc0 = 0; kc0 < 576; kc0 += 32) {
      short8 bv = *(const short8*)(bp + kc0);
      short8 a0 = *(const short8*)(a0p + kc0);
      short8 a1 = *(const short8*)(a1p + kc0);
      t0 = __builtin_amdgcn_mfma_f32_16x16x32_bf16(a0, bv, t0, 0, 0, 0);
      t1 = __builtin_amdgcn_mfma_f32_16x16x32_bf16(a1, bv, t1, 0, 0, 0);
    }
  }
  if ((r16 >> 2) == wave) {
#pragma unroll
    for (int r = 0; r < 4; r++) {
      omS[r16 * 29 + quad * 4 + r] = t0[r];
      int oc2 = 16 + quad * 4 + r;
      if (oc2 < 27) omS[r16 * 29 + oc2] = t1[r];
    }
  }

  // ---- P2.5: per-(p,k) sampling params, 36 lanes per wave, own pixels only ----
  if (lane < 36) {
    int p_loc = (lane * 7282) >> 16;  // lane/9
    int k = lane - p_loc * 9;
    int p = wave * 4 + p_loc;
    const float* ob = omS + p * 29;
    float oy = ob[2 * k], ox = ob[2 * k + 1], mm = ob[18 + k];
    float msk = 1.f / (1.f + __expf(-mm));
    int ky = (k * 11) >> 5;  // k/3
    int kx = k - 3 * ky;
    float py = (float)(h - 1 + ky) + oy;
    float px = (float)(w0 + p - 1 + kx) + ox;
    float y0f = floorf(py), x0f = floorf(px);
    float ly = py - y0f, lx = px - x0f;
    int y0 = (int)y0f, x0 = (int)x0f;
    int y1 = y0 + 1, x1 = x0 + 1;
    float lylx = ly * lx;
    float w11 = lylx * msk;
    float w10 = (ly - lylx) * msk;
    float w01 = (lx - lylx) * msk;
    float w00 = (1.f - ly - lx + lylx) * msk;
    bool y0v = (unsigned)y0 < (unsigned)HH, y1v = (unsigned)y1 < (unsigned)HH;
    bool x0v = (unsigned)x0 < (unsigned)WW, x1v = (unsigned)x1 < (unsigned)WW;
    int yc0 = min(max(y0, 0), HH - 1), yc1 = min(max(y1, 0), HH - 1);
    int xc0 = min(max(x0, 0), WW - 1), xc1 = min(max(x1, 0), WW - 1);
    Pw[p * 9 + k] = make_float4((y0v && x0v) ? w00 : 0.f, (y0v && x1v) ? w01 : 0.f,
                                (y1v && x0v) ? w10 : 0.f, (y1v && x1v) ? w11 : 0.f);
    Po[p * 9 + k] = make_int4((yc0 * WW + xc0) * CI, (yc0 * WW + xc1) * CI,
                              (yc1 * WW + xc0) * CI, (yc1 * WW + xc1) * CI);
  }
  __syncthreads();  // WAR: P2's SL reads vs P3's SL writes

  // ---- P3: gather + blend, params broadcast from LDS ----
#pragma unroll
  for (int i = 0; i < 4; i++) {
    int p = wave * 4 + i;
#pragma unroll
    for (int k = 0; k < 9; k++) {
      float4 wv = Pw[p * 9 + k];
      int4 ov = Po[p * 9 + k];
      float v00 = xb[ov.x + c];
      float v01 = xb[ov.y + c];
      float v10 = xb[ov.z + c];
      float v11 = xb[ov.w + c];
      float s = (v00 * wv.x + v01 * wv.y) + (v10 * wv.z + v11 * wv.w);
      SL[p * SLS + k * 64 + c] = __float2bfloat16(s);
    }
  }
  __syncthreads();

  // ---- P4: main einsum GEMM, bias in C-init, ReLU epilogue ----
  floatx4 acc = *(const floatx4*)(bias2 + wave * 16 + quad * 4);
  {
    const unsigned short* Ap = A + (wave * 16 + r16) * 576 + quad * 8;
    const __hip_bfloat16* Sp = &SL[r16 * SLS + quad * 8];
#pragma unroll
    for (int kc0 = 0; kc0 < 576; kc0 += 32) {
      short8 av = *(const short8*)(Ap + kc0);
      short8 bv = *(const short8*)(Sp + kc0);
      acc = __builtin_amdgcn_mfma_f32_16x16x32_bf16(av, bv, acc, 0, 0, 0);
    }
  }
  int p = r16;
#pragma unroll
  for (int r = 0; r < 4; r++) {
    int o = wave * 16 + quad * 4 + r;
    out[((b * CO + o) * HH + h) * WW + w0 + p] = fmaxf(acc[r], 0.f);
  }
}

extern "C" void kernel_launch(void* const* d_in, const int* in_sizes, int n_in,
                              void* d_out, int out_size, void* d_ws, size_t ws_size,
                              hipStream_t stream) {
  const float* x = (const float*)d_in[0];
  const float* w_off = (const float*)d_in[1];
  const float* b_off = (const float*)d_in[2];
  const float* weight = (const float*)d_in[3];
  const float* bias = (const float*)d_in[4];
  const float* gamma = (const float*)d_in[5];
  const float* beta = (const float*)d_in[6];
  const float* run_mean = (const float*)d_in[7];
  const float* run_var = (const float*)d_in[8];
  float* outp = (float*)d_out;

  char* ws = (char*)d_ws;
  float* xT = (float*)ws;                                  // 8,388,608 B
  unsigned short* A = (unsigned short*)(ws + 8388608);     //    73,728 B
  unsigned short* w2 = (unsigned short*)(ws + 8462336);    //    36,864 B
  float* bias2 = (float*)(ws + 8499200);                   //       256 B
  float* boff2 = (float*)(ws + 8499456);                   //       128 B

  setup_kernel<<<656, 256, 0, stream>>>(x, xT, weight, bias, gamma, beta,
                                        run_mean, run_var, w_off, b_off,
                                        A, w2, bias2, boff2);
  dcn3_kernel<<<2048, 256, 0, stream>>>(xT, w2, boff2, A, bias2, outp);
}

// Round 4
// 115.236 us; speedup vs baseline: 1.3138x; 1.3138x over previous
//
#include <hip/hip_runtime.h>
#include <hip/hip_bf16.h>

#define HH 128
#define WW 128
#define CI 64
#define CO 64
#define SLS 584  // LDS row stride in bf16 elems (576 + 8 pad)

typedef __attribute__((ext_vector_type(8))) short short8;
typedef __attribute__((ext_vector_type(4))) float floatx4;

__device__ __forceinline__ unsigned short f2bf(float f) {
  union { float f; unsigned u; } uu; uu.f = f;
  unsigned r = uu.u + 0x7FFFu + ((uu.u >> 16) & 1u);  // RNE
  return (unsigned short)(r >> 16);
}
__device__ __forceinline__ unsigned pack2bf(float lo, float hi) {
  return (unsigned)f2bf(lo) | ((unsigned)f2bf(hi) << 16);
}

// Blocks [0,512): NCHW fp32 -> NHWC bf16 transpose. Blocks [512,656): weight prep.
__global__ __launch_bounds__(256) void setup_kernel(
    const float* __restrict__ x, unsigned* __restrict__ xTb,  // bf16 pairs
    const float* __restrict__ weight, const float* __restrict__ bias,
    const float* __restrict__ gamma, const float* __restrict__ beta,
    const float* __restrict__ mean, const float* __restrict__ var,
    const float* __restrict__ w_off, const float* __restrict__ b_off,
    unsigned short* __restrict__ A, unsigned short* __restrict__ w2,
    float* __restrict__ bias2, float* __restrict__ boff2) {
  __shared__ float tile[64][65];
  int bid = blockIdx.x;
  if (bid < 512) {
    int w0 = (bid & 1) * 64;
    int h = (bid >> 1) & (HH - 1);
    int b = bid >> 8;
    int tc = threadIdx.x & 63;
    int tr = threadIdx.x >> 6;
#pragma unroll
    for (int i = 0; i < 16; i++) {
      int c = i * 4 + tr;
      tile[c][tc] = x[((b * CI + c) * HH + h) * WW + w0 + tc];
    }
    __syncthreads();
    int cp = threadIdx.x & 31;   // channel pair
    int wq = threadIdx.x >> 5;   // 0..7
#pragma unroll
    for (int jj = 0; jj < 8; jj++) {
      int wl = jj * 8 + wq;
      unsigned v = pack2bf(tile[2 * cp][wl], tile[2 * cp + 1][wl]);
      xTb[((b * HH + h) * WW + w0 + wl) * 32 + cp] = v;
    }
  } else {
    int idx = (bid - 512) * 256 + threadIdx.x;
    if (idx < 32) boff2[idx] = (idx < 27) ? b_off[idx] : 0.f;
    if (idx < CO * 576) {
      int o = idx / 576, kc = idx - o * 576;
      int k = kc >> 6, c = kc & 63;
      float inv = gamma[o] * rsqrtf(var[o] + 1e-5f);
      A[idx] = f2bf(weight[(o * CI + c) * 9 + k] * inv);
      if (kc == 0) bias2[o] = (bias[o] - mean[o]) * inv + beta[o];
      if (o < 27) w2[idx] = f2bf(w_off[o * 576 + c * 9 + k]);
      else if (o < 32) w2[idx] = 0;
    }
  }
}

// Fused DCN: 16 pixels/block, 256 thr = 4 waves. XCD slab swizzle for L2 locality.
// P1 patches(copy bf16) -> P2 offset GEMM (waves 0,1) -> P2.5 params -> P3 gather
// (2ch/lane) -> P4 main GEMM + BN + ReLU.
__global__ __launch_bounds__(256) void dcn4_kernel(
    const unsigned short* __restrict__ xTb, const unsigned short* __restrict__ w2,
    const float* __restrict__ boff2, const unsigned short* __restrict__ A,
    const float* __restrict__ bias2, float* __restrict__ out) {
  __shared__ __hip_bfloat16 SL[16 * SLS];
  __shared__ float omS[16 * 29];
  __shared__ float4 Pw[144];
  __shared__ int4 Po[144];

  int bid = blockIdx.x;
  // slab decode: XCD key (bid&7) -> h slab of 16 rows
  int s = bid & 7;
  int n = bid >> 3;           // 0..255
  int b = n >> 7;             // 0..1
  int rem = n & 127;
  int h = s * 16 + (rem >> 3);
  int w0 = (rem & 7) * 16;

  int tid = threadIdx.x;
  int lane = tid & 63;
  int wave = tid >> 6;
  int cp = lane & 31;         // channel pair: ch = 2*cp
  int ph = lane >> 5;         // pixel half-select
  const unsigned short* xb = xTb + b * (HH * WW * CI);

  // ---- P1: copy im2col patches (bf16, 2ch per lane, half-wave per pixel) ----
#pragma unroll
  for (int j = 0; j < 2; j++) {
    int p = wave * 4 + j * 2 + ph;
    int wpx = w0 + p;
#pragma unroll
    for (int dy = 0; dy < 3; dy++) {
      int y = h - 1 + dy;
      bool yok = (unsigned)y < (unsigned)HH;
#pragma unroll
      for (int dx = 0; dx < 3; dx++) {
        int xx = wpx - 1 + dx;
        unsigned v = 0;
        if (yok && (unsigned)xx < (unsigned)WW)
          v = *(const unsigned*)(xb + (y * WW + xx) * CI + 2 * cp);
        *(unsigned*)(&SL[p * SLS + (dy * 3 + dx) * 64 + 2 * cp]) = v;
      }
    }
  }
  __syncthreads();

  int r16 = lane & 15;
  int quad = lane >> 4;

  // ---- P2: offset GEMM, wave w in {0,1} computes oc tile w ----
  if (wave < 2) {
    floatx4 t = *(const floatx4*)(boff2 + wave * 16 + quad * 4);
    const unsigned short* ap = w2 + (wave * 16 + r16) * 576 + quad * 8;
    const __hip_bfloat16* bp = &SL[r16 * SLS + quad * 8];
#pragma unroll
    for (int kc0 = 0; kc0 < 576; kc0 += 32) {
      short8 av = *(const short8*)(ap + kc0);
      short8 bv = *(const short8*)(bp + kc0);
      t = __builtin_amdgcn_mfma_f32_16x16x32_bf16(av, bv, t, 0, 0, 0);
    }
#pragma unroll
    for (int r = 0; r < 4; r++) {
      int oc = wave * 16 + quad * 4 + r;
      if (oc < 27) omS[r16 * 29 + oc] = t[r];
    }
  }
  __syncthreads();  // omS ready + all P2 SL reads done (covers P3's WAR)

  // ---- P2.5: per-(p,k) sampling params, 36 lanes/wave, own pixels ----
  if (lane < 36) {
    int p_loc = (lane * 7282) >> 16;  // lane/9
    int k = lane - p_loc * 9;
    int p = wave * 4 + p_loc;
    const float* ob = omS + p * 29;
    float oy = ob[2 * k], ox = ob[2 * k + 1], mm = ob[18 + k];
    float msk = 1.f / (1.f + __expf(-mm));
    int ky = (k * 11) >> 5;  // k/3
    int kx = k - 3 * ky;
    float py = (float)(h - 1 + ky) + oy;
    float px = (float)(w0 + p - 1 + kx) + ox;
    float y0f = floorf(py), x0f = floorf(px);
    float ly = py - y0f, lx = px - x0f;
    int y0 = (int)y0f, x0 = (int)x0f;
    int y1 = y0 + 1, x1 = x0 + 1;
    float lylx = ly * lx;
    float w11 = lylx * msk;
    float w10 = (ly - lylx) * msk;
    float w01 = (lx - lylx) * msk;
    float w00 = (1.f - ly - lx + lylx) * msk;
    bool y0v = (unsigned)y0 < (unsigned)HH, y1v = (unsigned)y1 < (unsigned)HH;
    bool x0v = (unsigned)x0 < (unsigned)WW, x1v = (unsigned)x1 < (unsigned)WW;
    int yc0 = min(max(y0, 0), HH - 1), yc1 = min(max(y1, 0), HH - 1);
    int xc0 = min(max(x0, 0), WW - 1), xc1 = min(max(x1, 0), WW - 1);
    Pw[p * 9 + k] = make_float4((y0v && x0v) ? w00 : 0.f, (y0v && x1v) ? w01 : 0.f,
                                (y1v && x0v) ? w10 : 0.f, (y1v && x1v) ? w11 : 0.f);
    Po[p * 9 + k] = make_int4((yc0 * WW + xc0) * CI, (yc0 * WW + xc1) * CI,
                              (yc1 * WW + xc0) * CI, (yc1 * WW + xc1) * CI);
  }
  // no barrier: Pw/Po are read only by the wave that wrote them

  // ---- P3: gather (2 ch/lane) + blend + bf16 pack to SL ----
#pragma unroll
  for (int j = 0; j < 2; j++) {
    int p = wave * 4 + j * 2 + ph;
#pragma unroll
    for (int k = 0; k < 9; k++) {
      float4 wv = Pw[p * 9 + k];
      int4 ov = Po[p * 9 + k];
      int ch = 2 * cp;
      unsigned u00 = *(const unsigned*)(xb + ov.x + ch);
      unsigned u01 = *(const unsigned*)(xb + ov.y + ch);
      unsigned u10 = *(const unsigned*)(xb + ov.z + ch);
      unsigned u11 = *(const unsigned*)(xb + ov.w + ch);
      float lo = __uint_as_float(u00 << 16) * wv.x + __uint_as_float(u01 << 16) * wv.y +
                 __uint_as_float(u10 << 16) * wv.z + __uint_as_float(u11 << 16) * wv.w;
      float hi = __uint_as_float(u00 & 0xffff0000u) * wv.x + __uint_as_float(u01 & 0xffff0000u) * wv.y +
                 __uint_as_float(u10 & 0xffff0000u) * wv.z + __uint_as_float(u11 & 0xffff0000u) * wv.w;
      *(unsigned*)(&SL[p * SLS + k * 64 + ch]) = pack2bf(lo, hi);
    }
  }
  __syncthreads();

  // ---- P4: main GEMM, bias in C-init, ReLU ----
  floatx4 acc = *(const floatx4*)(bias2 + wave * 16 + quad * 4);
  {
    const unsigned short* Ap = A + (wave * 16 + r16) * 576 + quad * 8;
    const __hip_bfloat16* Sp = &SL[r16 * SLS + quad * 8];
#pragma unroll
    for (int kc0 = 0; kc0 < 576; kc0 += 32) {
      short8 av = *(const short8*)(Ap + kc0);
      short8 bv = *(const short8*)(Sp + kc0);
      acc = __builtin_amdgcn_mfma_f32_16x16x32_bf16(av, bv, acc, 0, 0, 0);
    }
  }
  int p = r16;
#pragma unroll
  for (int r = 0; r < 4; r++) {
    int o = wave * 16 + quad * 4 + r;
    out[((b * CO + o) * HH + h) * WW + w0 + p] = fmaxf(acc[r], 0.f);
  }
}

extern "C" void kernel_launch(void* const* d_in, const int* in_sizes, int n_in,
                              void* d_out, int out_size, void* d_ws, size_t ws_size,
                              hipStream_t stream) {
  const float* x = (const float*)d_in[0];
  const float* w_off = (const float*)d_in[1];
  const float* b_off = (const float*)d_in[2];
  const float* weight = (const float*)d_in[3];
  const float* bias = (const float*)d_in[4];
  const float* gamma = (const float*)d_in[5];
  const float* beta = (const float*)d_in[6];
  const float* run_mean = (const float*)d_in[7];
  const float* run_var = (const float*)d_in[8];
  float* outp = (float*)d_out;

  char* ws = (char*)d_ws;
  unsigned* xTb = (unsigned*)ws;                           // 4,194,304 B (bf16 NHWC)
  unsigned short* A = (unsigned short*)(ws + 4194304);     //    73,728 B
  unsigned short* w2 = (unsigned short*)(ws + 4268032);    //    36,864 B
  float* bias2 = (float*)(ws + 4304896);                   //       256 B
  float* boff2 = (float*)(ws + 4305152);                   //       128 B

  setup_kernel<<<656, 256, 0, stream>>>(x, xTb, weight, bias, gamma, beta,
                                        run_mean, run_var, w_off, b_off,
                                        A, w2, bias2, boff2);
  dcn4_kernel<<<2048, 256, 0, stream>>>((const unsigned short*)xTb, w2, boff2,
                                        A, bias2, outp);
}

// Round 5
// 113.993 us; speedup vs baseline: 1.3281x; 1.0109x over previous
//
#include <hip/hip_runtime.h>
#include <hip/hip_bf16.h>

#define HH 128
#define WW 128
#define CI 64
#define CO 64
#define SLS 584    // LDS row stride in bf16 elems (576 + 8 pad)
#define HALO_H 9   // image rows h-4 .. h+4
#define HALO_W 22  // image cols w0-3 .. w0+18
#define HPS 72     // shorts per halo pixel (64 ch + 8 pad)

typedef __attribute__((ext_vector_type(8))) short short8;
typedef __attribute__((ext_vector_type(4))) float floatx4;

__device__ __forceinline__ unsigned short f2bf(float f) {
  union { float f; unsigned u; } uu; uu.f = f;
  unsigned r = uu.u + 0x7FFFu + ((uu.u >> 16) & 1u);  // RNE
  return (unsigned short)(r >> 16);
}
__device__ __forceinline__ unsigned pack2bf(float lo, float hi) {
  return (unsigned)f2bf(lo) | ((unsigned)f2bf(hi) << 16);
}

// Blocks [0,512): NCHW fp32 -> NHWC bf16 transpose. Blocks [512,656): weight prep.
__global__ __launch_bounds__(256) void setup_kernel(
    const float* __restrict__ x, unsigned* __restrict__ xTb,
    const float* __restrict__ weight, const float* __restrict__ bias,
    const float* __restrict__ gamma, const float* __restrict__ beta,
    const float* __restrict__ mean, const float* __restrict__ var,
    const float* __restrict__ w_off, const float* __restrict__ b_off,
    unsigned short* __restrict__ A, unsigned short* __restrict__ w2,
    float* __restrict__ bias2, float* __restrict__ boff2) {
  __shared__ float tile[64][65];
  int bid = blockIdx.x;
  if (bid < 512) {
    int w0 = (bid & 1) * 64;
    int h = (bid >> 1) & (HH - 1);
    int b = bid >> 8;
    int tc = threadIdx.x & 63;
    int tr = threadIdx.x >> 6;
#pragma unroll
    for (int i = 0; i < 16; i++) {
      int c = i * 4 + tr;
      tile[c][tc] = x[((b * CI + c) * HH + h) * WW + w0 + tc];
    }
    __syncthreads();
    int cp = threadIdx.x & 31;
    int wq = threadIdx.x >> 5;
#pragma unroll
    for (int jj = 0; jj < 8; jj++) {
      int wl = jj * 8 + wq;
      unsigned v = pack2bf(tile[2 * cp][wl], tile[2 * cp + 1][wl]);
      xTb[((b * HH + h) * WW + w0 + wl) * 32 + cp] = v;
    }
  } else {
    int idx = (bid - 512) * 256 + threadIdx.x;
    if (idx < 32) boff2[idx] = (idx < 27) ? b_off[idx] : 0.f;
    if (idx < CO * 576) {
      int o = idx / 576, kc = idx - o * 576;
      int k = kc >> 6, c = kc & 63;
      float inv = gamma[o] * rsqrtf(var[o] + 1e-5f);
      A[idx] = f2bf(weight[(o * CI + c) * 9 + k] * inv);
      if (kc == 0) bias2[o] = (bias[o] - mean[o]) * inv + beta[o];
      if (o < 27) w2[idx] = f2bf(w_off[o * 576 + c * 9 + k]);
      else if (o < 32) w2[idx] = 0;
    }
  }
}

// Fused DCN, LDS-halo version. 16 pixels/block, 4 waves.
// P1 halo stage -> P2 offset GEMM (B from halo) -> P2.5 params -> P3 LDS gather ->
// P4 main GEMM + BN + ReLU.
__global__ __launch_bounds__(256) void dcn5_kernel(
    const unsigned short* __restrict__ xTb, const unsigned short* __restrict__ w2,
    const float* __restrict__ boff2, const unsigned short* __restrict__ A,
    const float* __restrict__ bias2, float* __restrict__ out) {
  __shared__ short halo[HALO_H * HALO_W * HPS];  // 28,512 B, zero-padded image patch
  __shared__ __hip_bfloat16 SL[16 * SLS];        // 18,688 B, sampled S
  __shared__ float omS[16 * 29];
  __shared__ float4 Pw[144];
  __shared__ uint2 Po[144];  // packed halo short-offsets of 4 corners

  int bid = blockIdx.x;
  int s = bid & 7;            // XCD key -> h slab
  int n = bid >> 3;
  int b = n >> 7;
  int rem = n & 127;
  int h = s * 16 + (rem >> 3);
  int w0 = (rem & 7) * 16;

  int tid = threadIdx.x;
  int lane = tid & 63;
  int wave = tid >> 6;
  int cp = lane & 31;
  int ph = lane >> 5;
  const unsigned short* xb = xTb + b * (HH * WW * CI);
  const uint4* xb4 = (const uint4*)xb;  // 8 uint4 per pixel

  // ---- P1: stage zero-padded halo (198 px x 8 chunks of 16B) ----
#pragma unroll
  for (int it = 0; it < 7; it++) {
    int e = it * 256 + tid;
    if (e < HALO_H * HALO_W * 8) {
      int pix = e >> 3, j = e & 7;
      int iy = (pix * 2979) >> 16;  // pix / 22
      int ix = pix - iy * 22;
      int y = h - 4 + iy, xx = w0 - 3 + ix;
      uint4 v = make_uint4(0, 0, 0, 0);
      if ((unsigned)y < (unsigned)HH && (unsigned)xx < (unsigned)WW)
        v = xb4[(y * WW + xx) * 8 + j];
      *(uint4*)&halo[pix * HPS + j * 8] = v;
    }
  }
  __syncthreads();

  int r16 = lane & 15;
  int quad = lane >> 4;

  // ---- P2: offset GEMM, wave w in {0,1} computes oc tile w; B from halo ----
  if (wave < 2) {
    floatx4 t = *(const floatx4*)(boff2 + wave * 16 + quad * 4);
    const short* ap = (const short*)(w2 + (wave * 16 + r16) * 576);
#pragma unroll
    for (int kk = 0; kk < 9; kk++) {
      int dy = kk / 3, dx = kk - 3 * (kk / 3);
      const short* hp = &halo[((3 + dy) * 22 + (r16 + 2 + dx)) * HPS];
      short8 b0 = *(const short8*)(hp + quad * 8);
      short8 b1 = *(const short8*)(hp + 32 + quad * 8);
      short8 a0 = *(const short8*)(ap + kk * 64 + quad * 8);
      short8 a1 = *(const short8*)(ap + kk * 64 + 32 + quad * 8);
      t = __builtin_amdgcn_mfma_f32_16x16x32_bf16(a0, b0, t, 0, 0, 0);
      t = __builtin_amdgcn_mfma_f32_16x16x32_bf16(a1, b1, t, 0, 0, 0);
    }
#pragma unroll
    for (int r = 0; r < 4; r++) {
      int oc = wave * 16 + quad * 4 + r;
      if (oc < 27) omS[r16 * 29 + oc] = t[r];
    }
  }
  __syncthreads();  // omS ready

  // ---- P2.5: per-(p,k) sampling params (validity folded via halo zero padding) ----
  if (lane < 36) {
    int p_loc = (lane * 7282) >> 16;  // lane/9
    int k = lane - p_loc * 9;
    int p = wave * 4 + p_loc;
    const float* ob = omS + p * 29;
    float oy = ob[2 * k], ox = ob[2 * k + 1], mm = ob[18 + k];
    float msk = 1.f / (1.f + __expf(-mm));
    int ky = (k * 11) >> 5;  // k/3
    int kx = k - 3 * ky;
    float py = (float)(h - 1 + ky) + oy;
    float px = (float)(w0 + p - 1 + kx) + ox;
    float y0f = floorf(py), x0f = floorf(px);
    float ly = py - y0f, lx = px - x0f;
    int y0 = (int)y0f, x0 = (int)x0f;
    float lylx = ly * lx;
    Pw[p * 9 + k] = make_float4((1.f - ly - lx + lylx) * msk, (lx - lylx) * msk,
                                (ly - lylx) * msk, lylx * msk);
    // halo-relative coords, clamped into halo (safe for |off| <~ 2; 8 sigma margin)
    int y0r = min(max(y0 - (h - 4), 0), HALO_H - 2);
    int x0r = min(max(x0 - (w0 - 3), 0), HALO_W - 2);
    unsigned p00 = (unsigned)((y0r * 22 + x0r) * HPS);
    Po[p * 9 + k] = make_uint2(p00 | ((p00 + HPS) << 16),
                               (p00 + 22 * HPS) | ((p00 + 23 * HPS) << 16));
  }
  // no barrier: Pw/Po consumed by the producing wave only

  // ---- P3: LDS gather (2 ch/lane) + blend + bf16 pack to SL ----
  const char* hb = (const char*)halo;
  int cb = cp * 4;  // byte offset of channel pair within a halo pixel
#pragma unroll
  for (int j = 0; j < 2; j++) {
    int p = wave * 4 + j * 2 + ph;
#pragma unroll
    for (int k = 0; k < 9; k++) {
      float4 wv = Pw[p * 9 + k];
      uint2 po = Po[p * 9 + k];
      unsigned u00 = *(const unsigned*)(hb + 2 * (po.x & 0xffffu) + cb);
      unsigned u01 = *(const unsigned*)(hb + 2 * (po.x >> 16) + cb);
      unsigned u10 = *(const unsigned*)(hb + 2 * (po.y & 0xffffu) + cb);
      unsigned u11 = *(const unsigned*)(hb + 2 * (po.y >> 16) + cb);
      float lo = __uint_as_float(u00 << 16) * wv.x + __uint_as_float(u01 << 16) * wv.y +
                 __uint_as_float(u10 << 16) * wv.z + __uint_as_float(u11 << 16) * wv.w;
      float hi = __uint_as_float(u00 & 0xffff0000u) * wv.x + __uint_as_float(u01 & 0xffff0000u) * wv.y +
                 __uint_as_float(u10 & 0xffff0000u) * wv.z + __uint_as_float(u11 & 0xffff0000u) * wv.w;
      *(unsigned*)(&SL[p * SLS + k * 64 + 2 * cp]) = pack2bf(lo, hi);
    }
  }
  __syncthreads();

  // ---- P4: main GEMM, bias in C-init, ReLU ----
  floatx4 acc = *(const floatx4*)(bias2 + wave * 16 + quad * 4);
  {
    const unsigned short* Ap = A + (wave * 16 + r16) * 576 + quad * 8;
    const __hip_bfloat16* Sp = &SL[r16 * SLS + quad * 8];
#pragma unroll
    for (int kc0 = 0; kc0 < 576; kc0 += 32) {
      short8 av = *(const short8*)(Ap + kc0);
      short8 bv = *(const short8*)(Sp + kc0);
      acc = __builtin_amdgcn_mfma_f32_16x16x32_bf16(av, bv, acc, 0, 0, 0);
    }
  }
  int p = r16;
#pragma unroll
  for (int r = 0; r < 4; r++) {
    int o = wave * 16 + quad * 4 + r;
    out[((b * CO + o) * HH + h) * WW + w0 + p] = fmaxf(acc[r], 0.f);
  }
}

extern "C" void kernel_launch(void* const* d_in, const int* in_sizes, int n_in,
                              void* d_out, int out_size, void* d_ws, size_t ws_size,
                              hipStream_t stream) {
  const float* x = (const float*)d_in[0];
  const float* w_off = (const float*)d_in[1];
  const float* b_off = (const float*)d_in[2];
  const float* weight = (const float*)d_in[3];
  const float* bias = (const float*)d_in[4];
  const float* gamma = (const float*)d_in[5];
  const float* beta = (const float*)d_in[6];
  const float* run_mean = (const float*)d_in[7];
  const float* run_var = (const float*)d_in[8];
  float* outp = (float*)d_out;

  char* ws = (char*)d_ws;
  unsigned* xTb = (unsigned*)ws;                           // 4,194,304 B (bf16 NHWC)
  unsigned short* A = (unsigned short*)(ws + 4194304);     //    73,728 B
  unsigned short* w2 = (unsigned short*)(ws + 4268032);    //    36,864 B
  float* bias2 = (float*)(ws + 4304896);                   //       256 B
  float* boff2 = (float*)(ws + 4305152);                   //       128 B

  setup_kernel<<<656, 256, 0, stream>>>(x, xTb, weight, bias, gamma, beta,
                                        run_mean, run_var, w_off, b_off,
                                        A, w2, bias2, boff2);
  dcn5_kernel<<<2048, 256, 0, stream>>>((const unsigned short*)xTb, w2, boff2,
                                        A, bias2, outp);
}

// Round 6
// 111.146 us; speedup vs baseline: 1.3621x; 1.0256x over previous
//
#include <hip/hip_runtime.h>
#include <hip/hip_bf16.h>

#define HH 128
#define WW 128
#define CI 64
#define CO 64
#define SLS 584    // LDS row stride in bf16 elems (576 + 8 pad)
#define A_HPS 72   // kernel-A halo shorts per pixel (64 ch + 8 pad, 16B aligned)
#define A_HW 130   // kernel-A halo width: image cols -1..128

typedef __attribute__((ext_vector_type(8))) short short8;
typedef __attribute__((ext_vector_type(4))) float floatx4;

__device__ __forceinline__ unsigned short f2bf(float f) {
  union { float f; unsigned u; } uu; uu.f = f;
  unsigned r = uu.u + 0x7FFFu + ((uu.u >> 16) & 1u);  // RNE
  return (unsigned short)(r >> 16);
}
__device__ __forceinline__ unsigned pack2bf(float lo, float hi) {
  return (unsigned)f2bf(lo) | ((unsigned)f2bf(hi) << 16);
}

// ---- prep: Wm[o][k*64+c] = weight*inv (bf16 64x576); w2[32][576]; bias2; boff2 ----
__global__ __launch_bounds__(256) void prep_kernel(
    const float* __restrict__ weight, const float* __restrict__ bias,
    const float* __restrict__ gamma, const float* __restrict__ beta,
    const float* __restrict__ mean, const float* __restrict__ var,
    const float* __restrict__ w_off, const float* __restrict__ b_off,
    unsigned short* __restrict__ Wm, unsigned short* __restrict__ w2,
    float* __restrict__ bias2, float* __restrict__ boff2) {
  int idx = blockIdx.x * 256 + threadIdx.x;
  if (idx < 32) boff2[idx] = (idx < 27) ? b_off[idx] : 0.f;
  if (idx >= CO * 576) return;
  int o = idx / 576, kc = idx - o * 576;
  int k = kc >> 6, c = kc & 63;
  float inv = gamma[o] * rsqrtf(var[o] + 1e-5f);
  Wm[idx] = f2bf(weight[(o * CI + c) * 9 + k] * inv);
  if (kc == 0) bias2[o] = (bias[o] - mean[o]) * inv + beta[o];
  if (o < 27) w2[idx] = f2bf(w_off[o * 576 + c * 9 + k]);
  else if (o < 32) w2[idx] = 0;
}

// ---- offA: per (b,h) row — stage 3-row halo (bf16), emit xTb row, offset GEMM -> om32 ----
// 256 blocks (1/CU), 256 threads = 4 waves.
__global__ __launch_bounds__(256) void offA_kernel(
    const float* __restrict__ x, unsigned* __restrict__ xTb_u,
    const unsigned short* __restrict__ w2, const float* __restrict__ boff2,
    float* __restrict__ om32) {
  __shared__ short halo[3 * A_HW * A_HPS];  // 56,160 B, zero-padded
  int bid = blockIdx.x;
  int s = bid & 7;              // XCD slab key
  int n = bid >> 3;             // 0..31
  int b = n >> 4;
  int h = s * 16 + (n & 15);
  int tid = threadIdx.x;
  int xx = tid & 127, cg = tid >> 7;

  // stage rows h-1..h+1, 4 channels per thread-pass, b64 LDS writes
#pragma unroll
  for (int y3 = 0; y3 < 3; y3++) {
    int y = h - 1 + y3;
    bool yok = (unsigned)y < (unsigned)HH;
    const float* xrow = x + ((long)(b * CI) * HH + y) * WW + xx;
#pragma unroll
    for (int cc = 0; cc < 8; cc++) {
      int c = cg * 32 + cc * 4;
      float f0 = 0.f, f1 = 0.f, f2 = 0.f, f3 = 0.f;
      if (yok) {
        f0 = xrow[(c + 0) * (HH * WW)];
        f1 = xrow[(c + 1) * (HH * WW)];
        f2 = xrow[(c + 2) * (HH * WW)];
        f3 = xrow[(c + 3) * (HH * WW)];
      }
      *(uint2*)&halo[(y3 * A_HW + xx + 1) * A_HPS + c] =
          make_uint2(pack2bf(f0, f1), pack2bf(f2, f3));
    }
  }
  // zero edge columns (px 0 and 129)
  if (tid < 96) {
    int row = tid >> 5;
    int rr = tid & 31;
    int px = (rr >> 4) ? (A_HW - 1) : 0;
    int q = rr & 15;
    *(uint2*)&halo[(row * A_HW + px) * A_HPS + q * 4] = make_uint2(0, 0);
  }
  __syncthreads();

  // emit xTb row h (bf16 NHWC pairs), coalesced
  {
    int cp = tid & 31;
#pragma unroll
    for (int it = 0; it < 16; it++) {
      int px = it * 8 + (tid >> 5);
      unsigned u = *(const unsigned*)&halo[(A_HW + px + 1) * A_HPS + 2 * cp];
      xTb_u[((b * HH + h) * WW + px) * 32 + cp] = u;
    }
  }

  // offset GEMM: M=32 (2 m-tiles), N=128 (8 n-tiles), K=576
  int lane = tid & 63, wave = tid >> 6;
  int r16 = lane & 15, quad = lane >> 4;
  int m16 = wave & 1;
  floatx4 binit = *(const floatx4*)(boff2 + m16 * 16 + quad * 4);
  const short* ap = (const short*)(w2 + (m16 * 16 + r16) * 576);
#pragma unroll
  for (int i = 0; i < 4; i++) {
    int nt = (wave >> 1) + 2 * i;
    floatx4 t = binit;
#pragma unroll
    for (int kk = 0; kk < 9; kk++) {
      int dy = kk / 3, dx = kk - 3 * (kk / 3);
      const short* hp = &halo[(dy * A_HW + nt * 16 + r16 + dx) * A_HPS];
      short8 b0 = *(const short8*)(hp + quad * 8);
      short8 b1 = *(const short8*)(hp + 32 + quad * 8);
      short8 a0 = *(const short8*)(ap + kk * 64 + quad * 8);
      short8 a1 = *(const short8*)(ap + kk * 64 + 32 + quad * 8);
      t = __builtin_amdgcn_mfma_f32_16x16x32_bf16(a0, b0, t, 0, 0, 0);
      t = __builtin_amdgcn_mfma_f32_16x16x32_bf16(a1, b1, t, 0, 0, 0);
    }
    float* orow = om32 + (long)(((b * HH + h) * WW) + nt * 16 + r16) * 32;
#pragma unroll
    for (int r = 0; r < 4; r++) {
      int oc = m16 * 16 + quad * 4 + r;
      if (oc < 27) orow[oc] = t[r];
    }
  }
}

// ---- dcnB: 32 px/block, params -> independent global gathers -> one barrier -> GEMM ----
__global__ __launch_bounds__(256) void dcnB_kernel(
    const unsigned short* __restrict__ xTb, const float* __restrict__ om32,
    const unsigned short* __restrict__ Wm, const float* __restrict__ bias2,
    float* __restrict__ out) {
  __shared__ __hip_bfloat16 SL[32 * SLS];  // 37,376 B
  __shared__ float4 Pw[288];
  __shared__ int4 Po[288];

  int bid = blockIdx.x;
  int s = bid & 7;
  int n = bid >> 3;             // 0..127
  int b = n >> 6;
  int rem = n & 63;
  int h = s * 16 + (rem >> 2);
  int w0 = (rem & 3) * 32;

  int tid = threadIdx.x, lane = tid & 63, wave = tid >> 6;
  const unsigned short* xb = xTb + b * (HH * WW * CI);
  int rowpix = (b * HH + h) * WW + w0;

  // params: 72 (p,k) tasks per wave for its 8 pixels (no barrier needed)
  for (int t2 = lane; t2 < 72; t2 += 64) {
    int p_loc = (t2 * 7282) >> 16;  // t2/9
    int k = t2 - p_loc * 9;
    int p = wave * 8 + p_loc;
    const float* ob = om32 + (long)(rowpix + p) * 32;
    float oy = ob[2 * k], ox = ob[2 * k + 1], mm = ob[18 + k];
    float msk = 1.f / (1.f + __expf(-mm));
    int ky = (k * 11) >> 5;  // k/3
    int kx = k - 3 * ky;
    float py = (float)(h - 1 + ky) + oy;
    float px = (float)(w0 + p - 1 + kx) + ox;
    float y0f = floorf(py), x0f = floorf(px);
    float ly = py - y0f, lx = px - x0f;
    int y0 = (int)y0f, x0 = (int)x0f;
    int y1 = y0 + 1, x1 = x0 + 1;
    float lylx = ly * lx;
    bool y0v = (unsigned)y0 < (unsigned)HH, y1v = (unsigned)y1 < (unsigned)HH;
    bool x0v = (unsigned)x0 < (unsigned)WW, x1v = (unsigned)x1 < (unsigned)WW;
    int yc0 = min(max(y0, 0), HH - 1), yc1 = min(max(y1, 0), HH - 1);
    int xc0 = min(max(x0, 0), WW - 1), xc1 = min(max(x1, 0), WW - 1);
    Pw[p * 9 + k] = make_float4((y0v && x0v) ? (1.f - ly - lx + lylx) * msk : 0.f,
                                (y0v && x1v) ? (lx - lylx) * msk : 0.f,
                                (y1v && x0v) ? (ly - lylx) * msk : 0.f,
                                (y1v && x1v) ? lylx * msk : 0.f);
    Po[p * 9 + k] = make_int4((yc0 * WW + xc0) * CI, (yc0 * WW + xc1) * CI,
                              (yc1 * WW + xc0) * CI, (yc1 * WW + xc1) * CI);
  }

  // gather: 8 px per wave, 144 independent b32 global loads per thread
  int cp = lane & 31, ph = lane >> 5;
  int ch = 2 * cp;
#pragma unroll
  for (int j = 0; j < 4; j++) {
    int p = wave * 8 + j * 2 + ph;
#pragma unroll
    for (int k = 0; k < 9; k++) {
      float4 wv = Pw[p * 9 + k];
      int4 ov = Po[p * 9 + k];
      unsigned u00 = *(const unsigned*)(xb + ov.x + ch);
      unsigned u01 = *(const unsigned*)(xb + ov.y + ch);
      unsigned u10 = *(const unsigned*)(xb + ov.z + ch);
      unsigned u11 = *(const unsigned*)(xb + ov.w + ch);
      float lo = __uint_as_float(u00 << 16) * wv.x + __uint_as_float(u01 << 16) * wv.y +
                 __uint_as_float(u10 << 16) * wv.z + __uint_as_float(u11 << 16) * wv.w;
      float hi = __uint_as_float(u00 & 0xffff0000u) * wv.x + __uint_as_float(u01 & 0xffff0000u) * wv.y +
                 __uint_as_float(u10 & 0xffff0000u) * wv.z + __uint_as_float(u11 & 0xffff0000u) * wv.w;
      *(unsigned*)(&SL[p * SLS + k * 64 + ch]) = pack2bf(lo, hi);
    }
  }

  // preload this wave's A-fragments (reused across both N-tiles)
  int r16 = lane & 15, quad = lane >> 4;
  short8 af[18];
  {
    const short* Ap = (const short*)(Wm + (wave * 16 + r16) * 576 + quad * 8);
#pragma unroll
    for (int i = 0; i < 18; i++) af[i] = *(const short8*)(Ap + 32 * i);
  }
  __syncthreads();  // the one barrier: SL complete

  // main GEMM: wave's 16 o x 2 N-tiles of 16 px, K=576; BN bias in C-init, ReLU
#pragma unroll
  for (int nt = 0; nt < 2; nt++) {
    floatx4 acc = *(const floatx4*)(bias2 + wave * 16 + quad * 4);
    const __hip_bfloat16* Sp = &SL[(nt * 16 + r16) * SLS + quad * 8];
#pragma unroll
    for (int i = 0; i < 18; i++) {
      short8 bv = *(const short8*)(Sp + 32 * i);
      acc = __builtin_amdgcn_mfma_f32_16x16x32_bf16(af[i], bv, acc, 0, 0, 0);
    }
    int o = wave * 16 + quad * 4;
#pragma unroll
    for (int r = 0; r < 4; r++) {
      out[((b * CO + o + r) * HH + h) * WW + w0 + nt * 16 + r16] = fmaxf(acc[r], 0.f);
    }
  }
}

extern "C" void kernel_launch(void* const* d_in, const int* in_sizes, int n_in,
                              void* d_out, int out_size, void* d_ws, size_t ws_size,
                              hipStream_t stream) {
  const float* x = (const float*)d_in[0];
  const float* w_off = (const float*)d_in[1];
  const float* b_off = (const float*)d_in[2];
  const float* weight = (const float*)d_in[3];
  const float* bias = (const float*)d_in[4];
  const float* gamma = (const float*)d_in[5];
  const float* beta = (const float*)d_in[6];
  const float* run_mean = (const float*)d_in[7];
  const float* run_var = (const float*)d_in[8];
  float* outp = (float*)d_out;

  char* ws = (char*)d_ws;
  unsigned* xTb = (unsigned*)ws;                           //  4,194,304 B (bf16 NHWC)
  float* om32 = (float*)(ws + 4194304);                    //  4,194,304 B
  unsigned short* Wm = (unsigned short*)(ws + 8388608);    //     73,728 B
  unsigned short* w2 = (unsigned short*)(ws + 8462336);    //     36,864 B
  float* bias2 = (float*)(ws + 8499200);                   //        256 B
  float* boff2 = (float*)(ws + 8499456);                   //        128 B

  prep_kernel<<<144, 256, 0, stream>>>(weight, bias, gamma, beta, run_mean, run_var,
                                       w_off, b_off, Wm, w2, bias2, boff2);
  offA_kernel<<<256, 256, 0, stream>>>(x, xTb, w2, boff2, om32);
  dcnB_kernel<<<1024, 256, 0, stream>>>((const unsigned short*)xTb, om32, Wm, bias2, outp);
}

// Round 8
// 109.398 us; speedup vs baseline: 1.3839x; 1.0160x over previous
//
#include <hip/hip_runtime.h>
#include <hip/hip_bf16.h>

#define HH 128
#define WW 128
#define CI 64
#define CO 64
#define SLS 584    // LDS row stride in bf16 elems (576 + 8 pad)
#define A_HPS 72   // halo shorts per pixel (64 ch + 8 pad, 144B = 9x16B aligned)
#define A_HW 66    // halo width: image cols w0-1 .. w0+64

typedef __attribute__((ext_vector_type(8))) short short8;
typedef __attribute__((ext_vector_type(4))) float floatx4;

__device__ __forceinline__ unsigned short f2bf(float f) {
  union { float f; unsigned u; } uu; uu.f = f;
  unsigned r = uu.u + 0x7FFFu + ((uu.u >> 16) & 1u);  // RNE
  return (unsigned short)(r >> 16);
}
__device__ __forceinline__ unsigned pack2bf(float lo, float hi) {
  return (unsigned)f2bf(lo) | ((unsigned)f2bf(hi) << 16);
}

// ---- prep: Wm[o][k*64+c]=weight*inv (bf16 64x576); w2[32][576]; bias2; boff2 ----
__global__ __launch_bounds__(256) void prep_kernel(
    const float* __restrict__ weight, const float* __restrict__ bias,
    const float* __restrict__ gamma, const float* __restrict__ beta,
    const float* __restrict__ mean, const float* __restrict__ var,
    const float* __restrict__ w_off, const float* __restrict__ b_off,
    unsigned short* __restrict__ Wm, unsigned short* __restrict__ w2,
    float* __restrict__ bias2, float* __restrict__ boff2) {
  int idx = blockIdx.x * 256 + threadIdx.x;
  if (idx < 32) boff2[idx] = (idx < 27) ? b_off[idx] : 0.f;
  if (idx >= CO * 576) return;
  int o = idx / 576, kc = idx - o * 576;
  int k = kc >> 6, c = kc & 63;
  float inv = gamma[o] * rsqrtf(var[o] + 1e-5f);
  Wm[idx] = f2bf(weight[(o * CI + c) * 9 + k] * inv);
  if (kc == 0) bias2[o] = (bias[o] - mean[o]) * inv + beta[o];
  if (o < 27) w2[idx] = f2bf(w_off[o * 576 + c * 9 + k]);
  else if (o < 32) w2[idx] = 0;
}

// ---- offA: per (b,h,half-row) — 3-row/66-col bf16 halo, emit xTb, offset GEMM ----
// 512 blocks (2/CU), 256 threads = 4 waves.
__global__ __launch_bounds__(256) void offA_kernel(
    const float* __restrict__ x, unsigned* __restrict__ xTb_u,
    const unsigned short* __restrict__ w2, const float* __restrict__ boff2,
    float* __restrict__ om32) {
  __shared__ short halo[3 * A_HW * A_HPS];  // 28,512 B, zero-padded
  int bid = blockIdx.x;
  int s = bid & 7;              // XCD slab key
  int n = bid >> 3;             // 0..63
  int b = n >> 5;
  int rest = n & 31;
  int h = s * 16 + (rest & 15);
  int w0 = (rest >> 4) * 64;
  int tid = threadIdx.x;

  // stage: 792 tasks = 3 rows x 66 px x 4 cgroups(16 ch); zeros for out-of-image
#pragma unroll
  for (int it = 0; it < 4; it++) {
    int t = it * 256 + tid;
    if (t < 792) {
      int row = t / 264;
      int r2 = t - row * 264;
      int cg4 = r2 / 66;
      int px = r2 - cg4 * 66;
      int y = h - 1 + row;
      int xi = w0 - 1 + px;
      int c0 = cg4 * 16;
      float f[16];
      if (((unsigned)y < (unsigned)HH) && ((unsigned)xi < (unsigned)WW)) {
        const float* xp = x + ((long)(b * CI + c0) * HH + y) * WW + xi;
#pragma unroll
        for (int q = 0; q < 16; q++) f[q] = xp[q * (HH * WW)];
      } else {
#pragma unroll
        for (int q = 0; q < 16; q++) f[q] = 0.f;
      }
      short* hp = &halo[(row * A_HW + px) * A_HPS + c0];
#pragma unroll
      for (int q = 0; q < 4; q++)  // uint2 = 4 shorts -> stride q*4 (bug was q*8)
        *(uint2*)(hp + q * 4) =
            make_uint2(pack2bf(f[4 * q], f[4 * q + 1]), pack2bf(f[4 * q + 2], f[4 * q + 3]));
    }
  }
  __syncthreads();

  // emit xTb for this block's 64 px (bf16 NHWC pairs, coalesced)
  {
    int cp = tid & 31;
    int pw = tid >> 5;
#pragma unroll
    for (int it = 0; it < 8; it++) {
      int px = it * 8 + pw;
      unsigned u = *(const unsigned*)&halo[(A_HW + px + 1) * A_HPS + 2 * cp];
      xTb_u[((b * HH + h) * WW + w0 + px) * 32 + cp] = u;
    }
  }

  // offset GEMM: M=32 (2 m-tiles), N=64 (4 n-tiles), K=576
  int lane = tid & 63, wave = tid >> 6;
  int r16 = lane & 15, quad = lane >> 4;
  int m16 = wave & 1;
  floatx4 binit = *(const floatx4*)(boff2 + m16 * 16 + quad * 4);
  const short* ap = (const short*)(w2 + (m16 * 16 + r16) * 576);
#pragma unroll
  for (int i = 0; i < 2; i++) {
    int nt = (wave >> 1) + 2 * i;
    floatx4 t = binit;
#pragma unroll
    for (int kk = 0; kk < 9; kk++) {
      int dy = kk / 3, dx = kk - 3 * (kk / 3);
      const short* hp = &halo[(dy * A_HW + nt * 16 + r16 + dx) * A_HPS];
      short8 b0 = *(const short8*)(hp + quad * 8);
      short8 b1 = *(const short8*)(hp + 32 + quad * 8);
      short8 a0 = *(const short8*)(ap + kk * 64 + quad * 8);
      short8 a1 = *(const short8*)(ap + kk * 64 + 32 + quad * 8);
      t = __builtin_amdgcn_mfma_f32_16x16x32_bf16(a0, b0, t, 0, 0, 0);
      t = __builtin_amdgcn_mfma_f32_16x16x32_bf16(a1, b1, t, 0, 0, 0);
    }
    float* orow = om32 + (long)((b * HH + h) * WW + w0 + nt * 16 + r16) * 32;
#pragma unroll
    for (int r = 0; r < 4; r++) {
      int oc = m16 * 16 + quad * 4 + r;
      if (oc < 27) orow[oc] = t[r];
    }
  }
}

// ---- dcnB: 16 px/block, 2048 blocks. params -> gathers -> 1 barrier -> GEMM ----
__global__ __launch_bounds__(256) void dcnB_kernel(
    const unsigned short* __restrict__ xTb, const float* __restrict__ om32,
    const unsigned short* __restrict__ Wm, const float* __restrict__ bias2,
    float* __restrict__ out) {
  __shared__ __hip_bfloat16 SL[16 * SLS];  // 18,688 B
  __shared__ float4 Pw[144];               //  2,304 B
  __shared__ int2 Po[144];                 //  1,152 B (off00, dx|dy<<16)

  int bid = blockIdx.x;
  int s = bid & 7;
  int n = bid >> 3;             // 0..255
  int b = n >> 7;
  int rem = n & 127;
  int h = s * 16 + (rem >> 3);
  int w0 = (rem & 7) * 16;

  int tid = threadIdx.x, lane = tid & 63, wave = tid >> 6;
  const unsigned short* xb = xTb + b * (HH * WW * CI);
  int rowpix = (b * HH + h) * WW + w0;

  // params: 36 (p,k) tasks per wave for its 4 pixels (intra-wave only)
  if (lane < 36) {
    int p_loc = (lane * 7282) >> 16;  // lane/9
    int k = lane - p_loc * 9;
    int p = wave * 4 + p_loc;
    const float* ob = om32 + (long)(rowpix + p) * 32;
    float oy = ob[2 * k], ox = ob[2 * k + 1], mm = ob[18 + k];
    float msk = 1.f / (1.f + __expf(-mm));
    int ky = (k * 11) >> 5;  // k/3
    int kx = k - 3 * ky;
    float py = (float)(h - 1 + ky) + oy;
    float px = (float)(w0 + p - 1 + kx) + ox;
    float y0f = floorf(py), x0f = floorf(px);
    float ly = py - y0f, lx = px - x0f;
    int y0 = (int)y0f, x0 = (int)x0f;
    int y1 = y0 + 1, x1 = x0 + 1;
    float lylx = ly * lx;
    bool y0v = (unsigned)y0 < (unsigned)HH, y1v = (unsigned)y1 < (unsigned)HH;
    bool x0v = (unsigned)x0 < (unsigned)WW, x1v = (unsigned)x1 < (unsigned)WW;
    int yc0 = min(max(y0, 0), HH - 1), yc1 = min(max(y1, 0), HH - 1);
    int xc0 = min(max(x0, 0), WW - 1), xc1 = min(max(x1, 0), WW - 1);
    Pw[p * 9 + k] = make_float4((y0v && x0v) ? (1.f - ly - lx + lylx) * msk : 0.f,
                                (y0v && x1v) ? (lx - lylx) * msk : 0.f,
                                (y1v && x0v) ? (ly - lylx) * msk : 0.f,
                                (y1v && x1v) ? lylx * msk : 0.f);
    int dxs = (xc1 - xc0) * CI;        // 0 or 64
    int dys = (yc1 - yc0) * WW * CI;   // 0 or 8192
    Po[p * 9 + k] = make_int2((yc0 * WW + xc0) * CI, dxs | (dys << 16));
  }

  // gather: 4 px per wave, 72 independent b32 global loads per thread
  int cp = lane & 31, ph = lane >> 5, ch = 2 * cp;
#pragma unroll
  for (int j = 0; j < 2; j++) {
    int p = wave * 4 + j * 2 + ph;
#pragma unroll
    for (int k = 0; k < 9; k++) {
      float4 wv = Pw[p * 9 + k];
      int2 po = Po[p * 9 + k];
      int o00 = po.x + ch;
      int dx = po.y & 0xffff;
      int dyv = po.y >> 16;
      unsigned u00 = *(const unsigned*)(xb + o00);
      unsigned u01 = *(const unsigned*)(xb + o00 + dx);
      unsigned u10 = *(const unsigned*)(xb + o00 + dyv);
      unsigned u11 = *(const unsigned*)(xb + o00 + dyv + dx);
      float lo = __uint_as_float(u00 << 16) * wv.x + __uint_as_float(u01 << 16) * wv.y +
                 __uint_as_float(u10 << 16) * wv.z + __uint_as_float(u11 << 16) * wv.w;
      float hi = __uint_as_float(u00 & 0xffff0000u) * wv.x + __uint_as_float(u01 & 0xffff0000u) * wv.y +
                 __uint_as_float(u10 & 0xffff0000u) * wv.z + __uint_as_float(u11 & 0xffff0000u) * wv.w;
      *(unsigned*)(&SL[p * SLS + k * 64 + ch]) = pack2bf(lo, hi);
    }
  }
  __syncthreads();  // the one barrier: SL complete

  // main GEMM: wave's 16 o x block's 16 px, K=576; BN bias in C-init, ReLU
  int r16 = lane & 15, quad = lane >> 4;
  floatx4 acc = *(const floatx4*)(bias2 + wave * 16 + quad * 4);
  const unsigned short* Ap = Wm + (wave * 16 + r16) * 576 + quad * 8;
  const __hip_bfloat16* Sp = &SL[r16 * SLS + quad * 8];
#pragma unroll
  for (int kc0 = 0; kc0 < 576; kc0 += 32) {
    short8 av = *(const short8*)(Ap + kc0);
    short8 bv = *(const short8*)(Sp + kc0);
    acc = __builtin_amdgcn_mfma_f32_16x16x32_bf16(av, bv, acc, 0, 0, 0);
  }
#pragma unroll
  for (int r = 0; r < 4; r++) {
    int o = wave * 16 + quad * 4 + r;
    out[((b * CO + o) * HH + h) * WW + w0 + r16] = fmaxf(acc[r], 0.f);
  }
}

extern "C" void kernel_launch(void* const* d_in, const int* in_sizes, int n_in,
                              void* d_out, int out_size, void* d_ws, size_t ws_size,
                              hipStream_t stream) {
  const float* x = (const float*)d_in[0];
  const float* w_off = (const float*)d_in[1];
  const float* b_off = (const float*)d_in[2];
  const float* weight = (const float*)d_in[3];
  const float* bias = (const float*)d_in[4];
  const float* gamma = (const float*)d_in[5];
  const float* beta = (const float*)d_in[6];
  const float* run_mean = (const float*)d_in[7];
  const float* run_var = (const float*)d_in[8];
  float* outp = (float*)d_out;

  char* ws = (char*)d_ws;
  unsigned* xTb = (unsigned*)ws;                           //  4,194,304 B (bf16 NHWC)
  float* om32 = (float*)(ws + 4194304);                    //  4,194,304 B
  unsigned short* Wm = (unsigned short*)(ws + 8388608);    //     73,728 B
  unsigned short* w2 = (unsigned short*)(ws + 8462336);    //     36,864 B
  float* bias2 = (float*)(ws + 8499200);                   //        256 B
  float* boff2 = (float*)(ws + 8499456);                   //        128 B

  prep_kernel<<<144, 256, 0, stream>>>(weight, bias, gamma, beta, run_mean, run_var,
                                       w_off, b_off, Wm, w2, bias2, boff2);
  offA_kernel<<<512, 256, 0, stream>>>(x, xTb, w2, boff2, om32);
  dcnB_kernel<<<2048, 256, 0, stream>>>((const unsigned short*)xTb, om32, Wm, bias2, outp);
}